// Round 11
// baseline (4269.625 us; speedup 1.0000x reference)
//
#include <hip/hip_runtime.h>
#include <stdint.h>

#define N_ACTIVE 200000
#define N_IN 64
#define N_OUT 64
#define K_FILT 27
#define R_PAIRS 100000
#define TOTP (K_FILT * R_PAIRS)          // 2,700,000
#define RB 128                           // output rows per block
#define NB ((N_ACTIVE + RB - 1) / RB)    // 1563
#define NBUCK (NB * K_FILT)              // 42,201
#define ELDS 2304
#define MAXG 256

#define CF_BLOCKS (N_ACTIVE * N_IN / 8 / 256)    // 6250
#define CW_BLOCKS K_FILT
#define HI_BLOCKS ((TOTP + 255) / 256)

typedef __bf16 bf16x8 __attribute__((ext_vector_type(8)));
typedef float f32x4 __attribute__((ext_vector_type(4)));

__global__ __launch_bounds__(256) void zero_ints(int* __restrict__ p, int n) {
    int i = blockIdx.x * 256 + threadIdx.x;
    if (i < n) p[i] = 0;
}

// ---------------------------------------------------------------------------
// fused prep: convert_feat | convert_wt | histogram
// ---------------------------------------------------------------------------
__global__ __launch_bounds__(256) void prep_fused(
    const float* __restrict__ feat, __bf16* __restrict__ featb,
    const float* __restrict__ wsrc, __bf16* __restrict__ wt,
    const int* __restrict__ out_idx, int* __restrict__ cntO)
{
    int bb = blockIdx.x, t = threadIdx.x;
    if (bb < CF_BLOCKS) {
        int i = bb * 256 + t;
        const f32x4* src = reinterpret_cast<const f32x4*>(feat) + 2 * (size_t)i;
        f32x4 v0 = __builtin_nontemporal_load(src);
        f32x4 v1 = __builtin_nontemporal_load(src + 1);
        bf16x8 o;
        o[0] = (__bf16)v0[0]; o[1] = (__bf16)v0[1]; o[2] = (__bf16)v0[2]; o[3] = (__bf16)v0[3];
        o[4] = (__bf16)v1[0]; o[5] = (__bf16)v1[1]; o[6] = (__bf16)v1[2]; o[7] = (__bf16)v1[3];
        reinterpret_cast<bf16x8*>(featb)[i] = o;
    } else if (bb < CF_BLOCKS + CW_BLOCKS) {
        int kf = bb - CF_BLOCKS;
        const float* wk = wsrc + kf * 4096;
        __bf16* wo = wt + kf * 4096;
        int o = t >> 2, i0 = (t & 3) * 16;
        bf16x8 a, b;
        #pragma unroll
        for (int j = 0; j < 8; ++j) a[j] = (__bf16)wk[(i0 + j) * 64 + o];
        #pragma unroll
        for (int j = 0; j < 8; ++j) b[j] = (__bf16)wk[(i0 + 8 + j) * 64 + o];
        *reinterpret_cast<bf16x8*>(wo + o * 64 + i0) = a;
        *reinterpret_cast<bf16x8*>(wo + o * 64 + i0 + 8) = b;
    } else {
        int p = (bb - CF_BLOCKS - CW_BLOCKS) * 256 + t;
        if (p < TOTP) {
            unsigned k = (unsigned)p / (unsigned)R_PAIRS;
            int b = (out_idx[p] >> 7) * K_FILT + (int)k;
            atomicAdd(&cntO[b], 1);
        }
    }
}

// ---- 2-level exclusive scan ----
__global__ __launch_bounds__(256) void scanA(const int* __restrict__ cnt,
                                             int* __restrict__ off,
                                             int* __restrict__ bsum, int n) {
    __shared__ int s[256];
    int t = threadIdx.x, base = blockIdx.x * 1024 + t * 4;
    int v[4], sum = 0;
    #pragma unroll
    for (int j = 0; j < 4; ++j) { v[j] = (base + j < n) ? cnt[base + j] : 0; sum += v[j]; }
    s[t] = sum;
    __syncthreads();
    #pragma unroll
    for (int d = 1; d < 256; d <<= 1) {
        int x = (t >= d) ? s[t - d] : 0;
        __syncthreads();
        s[t] += x;
        __syncthreads();
    }
    int run = s[t] - sum;
    #pragma unroll
    for (int j = 0; j < 4; ++j) { if (base + j < n) off[base + j] = run; run += v[j]; }
    if (t == 255) bsum[blockIdx.x] = s[255];
}

__global__ __launch_bounds__(256) void scanB(int* __restrict__ bsum, int nb) {
    __shared__ int s[256];
    int t = threadIdx.x;
    int v = (t < nb) ? bsum[t] : 0;
    s[t] = v;
    __syncthreads();
    #pragma unroll
    for (int d = 1; d < 256; d <<= 1) {
        int x = (t >= d) ? s[t - d] : 0;
        __syncthreads();
        s[t] += x;
        __syncthreads();
    }
    if (t < nb) bsum[t] = s[t] - v;
}

__global__ __launch_bounds__(256) void scanC(int* __restrict__ off,
                                             const int* __restrict__ bsum,
                                             int* __restrict__ cursor,
                                             int n, int total) {
    int base = blockIdx.x * 1024 + threadIdx.x * 4;
    int add = bsum[blockIdx.x];
    #pragma unroll
    for (int j = 0; j < 4; ++j) {
        int i = base + j;
        if (i < n) { int v = off[i] + add; off[i] = v; cursor[i] = v; }
    }
    if (base == 0) off[n] = total;
}

__global__ __launch_bounds__(256) void scatter_pack(const int* __restrict__ in_idx,
                                                    const int* __restrict__ out_idx,
                                                    int* __restrict__ cursO,
                                                    int* __restrict__ entries) {
    int p = blockIdx.x * 256 + threadIdx.x;
    if (p >= TOTP) return;
    unsigned k = (unsigned)p / (unsigned)R_PAIRS;
    int orow = out_idx[p];
    int iv = in_idx[p];
    int bkt = (orow >> 7) * K_FILT + (int)k;
    int pos = atomicAdd(&cursO[bkt], 1);
    entries[pos] = (iv << 7) | (orow & 127);
}

// ---------------------------------------------------------------------------
// clock probe: 20000 dependent FMAs, 8 waves/SIMD -> issue-bound.
// Expected ~133 us at 2.4 GHz (8 waves x 20000 x 2 cyc = 320K cyc/SIMD).
// ---------------------------------------------------------------------------
__global__ __launch_bounds__(256) void clockprobe(float* __restrict__ dummy) {
    float x = (float)threadIdx.x * 1e-6f;
    #pragma unroll 1
    for (int i = 0; i < 20000; ++i) x = fmaf(x, 1.0000001f, 0.5f);
    if (x == 12345.6789f) dummy[threadIdx.x] = x;   // never true; keeps chain live
}

// ---------------------------------------------------------------------------
// Ablation template. Chassis identical to r9 fallback conv.
// MODE 0: real (full, writes real out)     MODE 1: full -> dummy
// MODE 2: noA  (A = const, keep entry live; B+MFMA+scatter intact)
// MODE 3: noScatter (A+B+MFMA intact; no ors-LDENT, no ds_add; acc kept live)
// MODE 4: skeleton (descriptor walk + ja-LDENT only)
// ---------------------------------------------------------------------------
template<int MODE>
__global__ __launch_bounds__(256) void conv_abl(
    const __bf16* __restrict__ featb,
    const __bf16* __restrict__ wtb,
    const float* __restrict__ bias,
    const int* __restrict__ off,
    const int* __restrict__ entries,
    float* __restrict__ out)
{
    __shared__ float outT[RB][68];
    __shared__ int   eLds[ELDS];
    __shared__ int   sOff[K_FILT + 1];
    __shared__ int   descLds[MAXG];
    __shared__ int   gc[32];
    __shared__ int   gCount;

    const int b = blockIdx.x;
    const int t = threadIdx.x;
    const int w = t >> 6;
    const int lane = t & 63;
    const int lrow = lane & 15;
    const int lkB  = (lane >> 4) * 8;
    const int rg4  = (lane >> 4) * 4;
    const int bK = b * K_FILT;

    if (t < K_FILT + 1) sOff[t] = off[bK + t];
    {
        f32x4 z = {0.f, 0.f, 0.f, 0.f};
        f32x4* o4 = reinterpret_cast<f32x4*>(&outT[0][0]);
        for (int j = t; j < RB * 68 / 4; j += 256) o4[j] = z;
    }
    __syncthreads();

    const int blockStart = sOff[0];
    const int total = sOff[K_FILT] - blockStart;
    const int stged = total < ELDS ? total : ELDS;
    for (int i = t; i < stged; i += 256)
        eLds[i] = __builtin_nontemporal_load(&entries[blockStart + i]);

    if (t < K_FILT) gc[t] = (sOff[t + 1] - sOff[t] + 15) >> 4;
    __syncthreads();
    if (t == 0) {
        int s = 0;
        #pragma unroll
        for (int kf = 0; kf < K_FILT; ++kf) { int g = gc[kf]; gc[kf] = s; s += g; }
        gCount = s;
    }
    __syncthreads();
    if (t < K_FILT) {
        int base = sOff[t] - blockStart;
        int c = sOff[t + 1] - sOff[t];
        int s = gc[t];
        for (int j = 0, g = 0; j < c; j += 16, ++g) {
            int nv = c - j; if (nv > 16) nv = 16;
            descLds[s + g] = (t << 18) | ((base + j) << 5) | nv;
        }
    }
    __syncthreads();

    const int nG = gCount;
    int curKf = -1;
    bf16x8 bfrag[4][2];

#define LDENT(idx) ((idx) < stged ? eLds[(idx)] : entries[blockStart + (idx)])

    for (int g = w; g < nG; g += 4) {
        int d = descLds[g];
        int kf = d >> 18, sj = (d >> 5) & 0x1FFF, nv = d & 31;
        int ja = sj + (lrow < nv ? lrow : 0);
        int e = LDENT(ja);

        if constexpr (MODE == 4) {
            asm volatile("" :: "v"(e));     // keep entry-read live; nothing else
            continue;
        }

        if (kf != curKf) {
            curKf = kf;
            const __bf16* wk = wtb + kf * 4096;
            #pragma unroll
            for (int n = 0; n < 4; ++n) {
                bfrag[n][0] = *reinterpret_cast<const bf16x8*>(
                    wk + (n * 16 + lrow) * 64 + lkB);
                bfrag[n][1] = *reinterpret_cast<const bf16x8*>(
                    wk + (n * 16 + lrow) * 64 + 32 + lkB);
            }
        }

        bf16x8 a0, a1;
        if constexpr (MODE == 2) {
            asm volatile("" :: "v"(e));     // keep entry-read live
            #pragma unroll
            for (int j = 0; j < 8; ++j) { a0[j] = (__bf16)1.0f; a1[j] = (__bf16)1.0f; }
        } else {
            const __bf16* ap = featb + (size_t)(e >> 7) * 64 + lkB;
            a0 = *reinterpret_cast<const bf16x8*>(ap);
            a1 = *reinterpret_cast<const bf16x8*>(ap + 32);
        }

        f32x4 acc[4];
        #pragma unroll
        for (int n = 0; n < 4; ++n) {
            acc[n] = __builtin_amdgcn_mfma_f32_16x16x32_bf16(
                a0, bfrag[n][0], (f32x4){0.f, 0.f, 0.f, 0.f}, 0, 0, 0);
            acc[n] = __builtin_amdgcn_mfma_f32_16x16x32_bf16(
                a1, bfrag[n][1], acc[n], 0, 0, 0);
        }

        if constexpr (MODE == 3) {
            #pragma unroll
            for (int n = 0; n < 4; ++n)
                #pragma unroll
                for (int r = 0; r < 4; ++r)
                    asm volatile("" :: "v"(acc[n][r]));   // keep MFMA live
        } else {
            #pragma unroll
            for (int r = 0; r < 4; ++r) {
                int eo = LDENT(sj + rg4 + r);
                int ors = eo & 127;
                if (rg4 + r < nv) {
                    #pragma unroll
                    for (int n = 0; n < 4; ++n)
                        atomicAdd(&outT[ors][n * 16 + lrow], acc[n][r]);
                }
            }
        }
    }
#undef LDENT

    __syncthreads();
    const int rowBase = b * RB;
    for (int j = t; j < RB * 64 / 4; j += 256) {
        int r = j >> 4, c = (j & 15) * 4;
        int gr = rowBase + r;
        if (gr < N_ACTIVE) {
            f32x4 bv = *reinterpret_cast<const f32x4*>(&bias[c]);
            f32x4 v  = *reinterpret_cast<const f32x4*>(&outT[r][c]);
            v += bv;
            __builtin_nontemporal_store(v, reinterpret_cast<f32x4*>(&out[gr * 64 + c]));
        }
    }
}

extern "C" void kernel_launch(void* const* d_in, const int* in_sizes, int n_in,
                              void* d_out, int out_size, void* d_ws, size_t ws_size,
                              hipStream_t stream) {
    const float* feat    = (const float*)d_in[0];
    const float* weight  = (const float*)d_in[1];
    const float* bias    = (const float*)d_in[2];
    const int*   in_idx  = (const int*)d_in[3];
    const int*   out_idx = (const int*)d_in[4];
    float* out = (float*)d_out;

    const size_t FB_BYTES = (size_t)N_ACTIVE * 64 * 2;      // 25,600,000
    const size_t WT_BYTES = (size_t)K_FILT * 4096 * 2;      //    221,184
    char* wsb = (char*)d_ws;
    __bf16* featb = (__bf16*)wsb;
    __bf16* wtb   = (__bf16*)(wsb + FB_BYTES);
    int* ip       = (int*)(wsb + FB_BYTES + WT_BYTES);
    int* cntO = ip;                      ip += NBUCK;
    int* cursO = ip;                     ip += NBUCK;
    int* offO = ip;                      ip += NBUCK + 1;
    int* bsumO = ip;                     ip += 256;
    int* entries = ip;                   ip += TOTP;
    float* dummy = (float*)ip;           // N_ACTIVE*64 floats = 51.2 MB scratch

    const int NSB_O = (NBUCK + 1023) / 1024;       // 42

    zero_ints<<<dim3((NBUCK + 255) / 256), dim3(256), 0, stream>>>(cntO, NBUCK);
    prep_fused<<<dim3(CF_BLOCKS + CW_BLOCKS + HI_BLOCKS), dim3(256), 0, stream>>>(
        feat, featb, weight, wtb, out_idx, cntO);
    scanA<<<dim3(NSB_O), dim3(256), 0, stream>>>(cntO, offO, bsumO, NBUCK);
    scanB<<<dim3(1), dim3(256), 0, stream>>>(bsumO, NSB_O);
    scanC<<<dim3(NSB_O), dim3(256), 0, stream>>>(offO, bsumO, cursO, NBUCK, TOTP);
    scatter_pack<<<dim3((TOTP + 255) / 256), dim3(256), 0, stream>>>(
        in_idx, out_idx, cursO, entries);

    // ---- diagnostics (write to ws scratch only) ----
    clockprobe<<<dim3(2048), dim3(256), 0, stream>>>(dummy);
    conv_abl<1><<<dim3(NB), dim3(256), 0, stream>>>(featb, wtb, bias, offO, entries, dummy);
    conv_abl<2><<<dim3(NB), dim3(256), 0, stream>>>(featb, wtb, bias, offO, entries, dummy);
    conv_abl<3><<<dim3(NB), dim3(256), 0, stream>>>(featb, wtb, bias, offO, entries, dummy);
    conv_abl<4><<<dim3(NB), dim3(256), 0, stream>>>(featb, wtb, bias, offO, entries, dummy);

    // ---- real kernel (validated output) ----
    conv_abl<0><<<dim3(NB), dim3(256), 0, stream>>>(featb, wtb, bias, offO, entries, out);
}

// Round 12
// 665.655 us; speedup vs baseline: 6.4142x; 6.4142x over previous
//
#include <hip/hip_runtime.h>
#include <stdint.h>

#define N_ACTIVE 200000
#define N_IN 64
#define N_OUT 64
#define K_FILT 27
#define R_PAIRS 100000
#define TOTP (K_FILT * R_PAIRS)          // 2,700,000
#define NSLOT (N_ACTIVE * K_FILT)        // 5,400,000 slots (row, kf)

#define CF_BLOCKS (N_ACTIVE * N_IN / 8 / 256)    // 6250
#define CW_BLOCKS K_FILT

typedef __bf16 bf16x8 __attribute__((ext_vector_type(8)));
typedef float f32x4 __attribute__((ext_vector_type(4)));

// ---------------------------------------------------------------------------
// convert: features fp32->bf16 | weight fp32 [k][i][o] -> bf16 Wt[k][o][i]
// ---------------------------------------------------------------------------
__global__ __launch_bounds__(256) void prep_convert(
    const float* __restrict__ feat, __bf16* __restrict__ featb,
    const float* __restrict__ wsrc, __bf16* __restrict__ wt)
{
    int bb = blockIdx.x, t = threadIdx.x;
    if (bb < CF_BLOCKS) {
        int i = bb * 256 + t;
        const f32x4* src = reinterpret_cast<const f32x4*>(feat) + 2 * (size_t)i;
        f32x4 v0 = __builtin_nontemporal_load(src);
        f32x4 v1 = __builtin_nontemporal_load(src + 1);
        bf16x8 o;
        o[0] = (__bf16)v0[0]; o[1] = (__bf16)v0[1]; o[2] = (__bf16)v0[2]; o[3] = (__bf16)v0[3];
        o[4] = (__bf16)v1[0]; o[5] = (__bf16)v1[1]; o[6] = (__bf16)v1[2]; o[7] = (__bf16)v1[3];
        reinterpret_cast<bf16x8*>(featb)[i] = o;
    } else {
        int kf = bb - CF_BLOCKS;
        const float* wk = wsrc + kf * 4096;
        __bf16* wo = wt + kf * 4096;
        int o = t >> 2, i0 = (t & 3) * 16;
        bf16x8 a, b;
        #pragma unroll
        for (int j = 0; j < 8; ++j) a[j] = (__bf16)wk[(i0 + j) * 64 + o];
        #pragma unroll
        for (int j = 0; j < 8; ++j) b[j] = (__bf16)wk[(i0 + 8 + j) * 64 + o];
        *reinterpret_cast<bf16x8*>(wo + o * 64 + i0) = a;
        *reinterpret_cast<bf16x8*>(wo + o * 64 + i0 + 8) = b;
    }
}

// ---------------------------------------------------------------------------
// claim: slot = out_row*27 + kf. 1st/2nd/3rd entry -> slot tables; 4th+ ->
// overflow list. Sum over {tables + list} == all pairs, any race order.
// ---------------------------------------------------------------------------
__global__ __launch_bounds__(256) void claim_pairs(
    const int* __restrict__ in_idx, const int* __restrict__ out_idx,
    int* __restrict__ slotCnt,
    int* __restrict__ slot1, int* __restrict__ slot2, int* __restrict__ slot3,
    int2* __restrict__ ovf, int* __restrict__ ovfCur)
{
    int p = blockIdx.x * 256 + threadIdx.x;
    if (p >= TOTP) return;
    unsigned k = (unsigned)p / (unsigned)R_PAIRS;
    int row = out_idx[p];
    int iv  = in_idx[p];
    int slot = row * K_FILT + (int)k;
    int c = atomicAdd(&slotCnt[slot], 1);
    if (c == 0)      slot1[slot] = iv;
    else if (c == 1) slot2[slot] = iv;
    else if (c == 2) slot3[slot] = iv;
    else {
        int q = atomicAdd(ovfCur, 1);
        ovf[q] = make_int2(slot, iv);
    }
}

// ---------------------------------------------------------------------------
// conv: each wave owns 16 out rows. For kf=0..26: lane (m=lane&15, kg=lane>>4)
// builds A[m][k-slice] = sum of feat rows claimed for (row m, kf) (fp32 merge
// for duplicates), B = Wt[kf] fragments from global (L2-hot), and the MFMA
// accumulator CHAINS across all 27 kf. No LDS, no atomics, no barriers.
// MFMA layouts r3-verified: A row=lane&15, k=(lane>>4)*8; C/D col=lane&15,
// row=(lane>>4)*4+reg. Output written exactly once (covers poison) + bias.
// ---------------------------------------------------------------------------
__global__ __launch_bounds__(256) void conv_slots(
    const __bf16* __restrict__ featb,   // [N_ACTIVE][64] bf16
    const __bf16* __restrict__ wtb,     // [K][o][i] bf16
    const float* __restrict__ bias,     // [64]
    const int* __restrict__ slotCnt,
    const int* __restrict__ slot1, const int* __restrict__ slot2,
    const int* __restrict__ slot3,
    float* __restrict__ out)            // [N_ACTIVE][64] fp32
{
    const int t = threadIdx.x;
    const int w = t >> 6;
    const int lane = t & 63;
    const int lrow = lane & 15;          // A/out row slot within tile
    const int kg   = lane >> 4;          // k-slice group (0..3)
    const int rowBase = blockIdx.x * 64 + w * 16;
    const int slotBase = (rowBase + lrow) * K_FILT;

    f32x4 acc0 = {0.f,0.f,0.f,0.f}, acc1 = acc0, acc2 = acc0, acc3 = acc0;

    const float b0 = bias[lrow], b1 = bias[16 + lrow],
                b2 = bias[32 + lrow], b3 = bias[48 + lrow];

    for (int kf = 0; kf < K_FILT; ++kf) {
        // ---- B fragments (8 x 16B, coalesced, L2-hot: 216 KB total) ----
        const __bf16* wk = wtb + kf * 4096;
        bf16x8 bf00 = *reinterpret_cast<const bf16x8*>(wk + (lrow)      * 64 + kg * 8);
        bf16x8 bf01 = *reinterpret_cast<const bf16x8*>(wk + (lrow)      * 64 + 32 + kg * 8);
        bf16x8 bf10 = *reinterpret_cast<const bf16x8*>(wk + (16 + lrow) * 64 + kg * 8);
        bf16x8 bf11 = *reinterpret_cast<const bf16x8*>(wk + (16 + lrow) * 64 + 32 + kg * 8);
        bf16x8 bf20 = *reinterpret_cast<const bf16x8*>(wk + (32 + lrow) * 64 + kg * 8);
        bf16x8 bf21 = *reinterpret_cast<const bf16x8*>(wk + (32 + lrow) * 64 + 32 + kg * 8);
        bf16x8 bf30 = *reinterpret_cast<const bf16x8*>(wk + (48 + lrow) * 64 + kg * 8);
        bf16x8 bf31 = *reinterpret_cast<const bf16x8*>(wk + (48 + lrow) * 64 + 32 + kg * 8);

        // ---- A build: slot walk (L1-hot after kf=0: 16 rows x 27 words) ----
        int slot = slotBase + kf;
        int c  = slotCnt[slot];
        int i1 = slot1[slot];
        int addr = (c > 0) ? i1 : 0;
        const __bf16* ap = featb + (size_t)addr * 64 + kg * 8;
        bf16x8 x0 = *reinterpret_cast<const bf16x8*>(ap);
        bf16x8 x1 = *reinterpret_cast<const bf16x8*>(ap + 32);

        if (__any(c > 1)) {                 // rare-ish: fp32 merge of duplicates
            if (c > 1) {
                int i2 = slot2[slot];
                const __bf16* bp = featb + (size_t)i2 * 64 + kg * 8;
                bf16x8 y0 = *reinterpret_cast<const bf16x8*>(bp);
                bf16x8 y1 = *reinterpret_cast<const bf16x8*>(bp + 32);
                float f0[8], f1[8];
                #pragma unroll
                for (int j = 0; j < 8; ++j) {
                    f0[j] = (float)x0[j] + (float)y0[j];
                    f1[j] = (float)x1[j] + (float)y1[j];
                }
                if (c > 2) {
                    int i3 = slot3[slot];
                    const __bf16* cp = featb + (size_t)i3 * 64 + kg * 8;
                    bf16x8 z0 = *reinterpret_cast<const bf16x8*>(cp);
                    bf16x8 z1 = *reinterpret_cast<const bf16x8*>(cp + 32);
                    #pragma unroll
                    for (int j = 0; j < 8; ++j) {
                        f0[j] += (float)z0[j];
                        f1[j] += (float)z1[j];
                    }
                }
                #pragma unroll
                for (int j = 0; j < 8; ++j) {
                    x0[j] = (__bf16)f0[j];
                    x1[j] = (__bf16)f1[j];
                }
            }
        }
        if (c <= 0) {
            #pragma unroll
            for (int j = 0; j < 8; ++j) { x0[j] = (__bf16)0.f; x1[j] = (__bf16)0.f; }
        }

        // ---- chained MFMA: acc += A(kf) * W(kf) ----
        acc0 = __builtin_amdgcn_mfma_f32_16x16x32_bf16(x0, bf00, acc0, 0, 0, 0);
        acc0 = __builtin_amdgcn_mfma_f32_16x16x32_bf16(x1, bf01, acc0, 0, 0, 0);
        acc1 = __builtin_amdgcn_mfma_f32_16x16x32_bf16(x0, bf10, acc1, 0, 0, 0);
        acc1 = __builtin_amdgcn_mfma_f32_16x16x32_bf16(x1, bf11, acc1, 0, 0, 0);
        acc2 = __builtin_amdgcn_mfma_f32_16x16x32_bf16(x0, bf20, acc2, 0, 0, 0);
        acc2 = __builtin_amdgcn_mfma_f32_16x16x32_bf16(x1, bf21, acc2, 0, 0, 0);
        acc3 = __builtin_amdgcn_mfma_f32_16x16x32_bf16(x0, bf30, acc3, 0, 0, 0);
        acc3 = __builtin_amdgcn_mfma_f32_16x16x32_bf16(x1, bf31, acc3, 0, 0, 0);
    }

    // ---- epilogue: C row = kg*4+r, col = n*16+lrow; write once + bias ----
    #pragma unroll
    for (int r = 0; r < 4; ++r) {
        int gr = rowBase + kg * 4 + r;
        float* orow = out + (size_t)gr * 64;
        orow[lrow]      = acc0[r] + b0;
        orow[16 + lrow] = acc1[r] + b1;
        orow[32 + lrow] = acc2[r] + b2;
        orow[48 + lrow] = acc3[r] + b3;
    }
}

// ---------------------------------------------------------------------------
// cleanup: overflow entries (4th+ duplicate per slot, E ~ 10K on random data).
// 64 threads = 64 out cols; dot(feat[in], Wt[kf][o]) + global fp32 atomicAdd.
// ---------------------------------------------------------------------------
__global__ __launch_bounds__(64) void ovf_cleanup(
    const __bf16* __restrict__ featb, const __bf16* __restrict__ wtb,
    const int2* __restrict__ ovf, const int* __restrict__ ovfCur,
    float* __restrict__ out)
{
    const int n = *ovfCur;
    const int lane = threadIdx.x;
    for (int e = blockIdx.x; e < n; e += gridDim.x) {
        int2 v = ovf[e];
        int slot = v.x, in = v.y;
        int row = slot / K_FILT;
        int kf  = slot - row * K_FILT;
        const __bf16* fp = featb + (size_t)in * 64;
        const __bf16* wp = wtb + kf * 4096 + lane * 64;
        float s = 0.f;
        #pragma unroll
        for (int j = 0; j < 8; ++j) {
            bf16x8 fv = *reinterpret_cast<const bf16x8*>(fp + j * 8);
            bf16x8 wv = *reinterpret_cast<const bf16x8*>(wp + j * 8);
            #pragma unroll
            for (int q = 0; q < 8; ++q) s += (float)fv[q] * (float)wv[q];
        }
        atomicAdd(&out[(size_t)row * 64 + lane], s);
    }
}

extern "C" void kernel_launch(void* const* d_in, const int* in_sizes, int n_in,
                              void* d_out, int out_size, void* d_ws, size_t ws_size,
                              hipStream_t stream) {
    const float* feat    = (const float*)d_in[0];
    const float* weight  = (const float*)d_in[1];
    const float* bias    = (const float*)d_in[2];
    const int*   in_idx  = (const int*)d_in[3];
    const int*   out_idx = (const int*)d_in[4];
    float* out = (float*)d_out;

    // ---- workspace layout (~134 MB) ----
    char* wsb = (char*)d_ws;
    __bf16* featb  = (__bf16*)wsb;                                  // 25,600,000
    __bf16* wtb    = (__bf16*)(wsb + 25600000);                     //    221,184
    int*  slotCnt  = (int*) (wsb + 25600000 + 221184);              // 21,600,000
    int*  slot1    = slotCnt + NSLOT;                               // 21,600,000
    int*  slot2    = slot1 + NSLOT;                                 // 21,600,000
    int*  slot3    = slot2 + NSLOT;                                 // 21,600,000
    int*  ovfCur   = slot3 + NSLOT;                                 // 16 B (padded)
    int2* ovf      = (int2*)(ovfCur + 4);                           // 21,600,000

    hipMemsetAsync(slotCnt, 0, (size_t)NSLOT * 4, stream);
    hipMemsetAsync(ovfCur, 0, 16, stream);

    prep_convert<<<dim3(CF_BLOCKS + CW_BLOCKS), dim3(256), 0, stream>>>(
        feat, featb, weight, wtb);
    claim_pairs<<<dim3((TOTP + 255) / 256), dim3(256), 0, stream>>>(
        in_idx, out_idx, slotCnt, slot1, slot2, slot3, ovf, ovfCur);
    conv_slots<<<dim3(N_ACTIVE / 64), dim3(256), 0, stream>>>(
        featb, wtb, bias, slotCnt, slot1, slot2, slot3, out);
    ovf_cleanup<<<dim3(2048), dim3(64), 0, stream>>>(featb, wtb, ovf, ovfCur, out);
}

// Round 13
// 664.504 us; speedup vs baseline: 6.4253x; 1.0017x over previous
//
#include <hip/hip_runtime.h>
#include <stdint.h>

#define N_ACTIVE 200000
#define N_IN 64
#define N_OUT 64
#define K_FILT 27
#define R_PAIRS 100000
#define TOTP (K_FILT * R_PAIRS)          // 2,700,000
#define NSLOT (N_ACTIVE * K_FILT)        // 5,400,000 slots (row, kf)

#define CF_BLOCKS (N_ACTIVE * N_IN / 8 / 256)    // 6250
#define CW_BLOCKS K_FILT                          // 27
#define CL_BLOCKS ((TOTP + 255) / 256)            // 10547

typedef __bf16 bf16x8 __attribute__((ext_vector_type(8)));
typedef float f32x4 __attribute__((ext_vector_type(4)));

// ---------------------------------------------------------------------------
// fused prep: convert_feat | convert_wt | claim (slot tables + overflow)
// ---------------------------------------------------------------------------
__global__ __launch_bounds__(256) void prep_fused(
    const float* __restrict__ feat, __bf16* __restrict__ featb,
    const float* __restrict__ wsrc, __bf16* __restrict__ wt,
    const int* __restrict__ in_idx, const int* __restrict__ out_idx,
    int* __restrict__ slotCnt,
    int* __restrict__ slot1, int* __restrict__ slot2, int* __restrict__ slot3,
    int2* __restrict__ ovf, int* __restrict__ ovfCur)
{
    int bb = blockIdx.x, t = threadIdx.x;
    if (bb < CF_BLOCKS) {
        int i = bb * 256 + t;
        const f32x4* src = reinterpret_cast<const f32x4*>(feat) + 2 * (size_t)i;
        f32x4 v0 = __builtin_nontemporal_load(src);
        f32x4 v1 = __builtin_nontemporal_load(src + 1);
        bf16x8 o;
        o[0] = (__bf16)v0[0]; o[1] = (__bf16)v0[1]; o[2] = (__bf16)v0[2]; o[3] = (__bf16)v0[3];
        o[4] = (__bf16)v1[0]; o[5] = (__bf16)v1[1]; o[6] = (__bf16)v1[2]; o[7] = (__bf16)v1[3];
        reinterpret_cast<bf16x8*>(featb)[i] = o;
    } else if (bb < CF_BLOCKS + CW_BLOCKS) {
        int kf = bb - CF_BLOCKS;
        const float* wk = wsrc + kf * 4096;
        __bf16* wo = wt + kf * 4096;
        int o = t >> 2, i0 = (t & 3) * 16;
        bf16x8 a, b;
        #pragma unroll
        for (int j = 0; j < 8; ++j) a[j] = (__bf16)wk[(i0 + j) * 64 + o];
        #pragma unroll
        for (int j = 0; j < 8; ++j) b[j] = (__bf16)wk[(i0 + 8 + j) * 64 + o];
        *reinterpret_cast<bf16x8*>(wo + o * 64 + i0) = a;
        *reinterpret_cast<bf16x8*>(wo + o * 64 + i0 + 8) = b;
    } else {
        int p = (bb - CF_BLOCKS - CW_BLOCKS) * 256 + t;
        if (p < TOTP) {
            unsigned k = (unsigned)p / (unsigned)R_PAIRS;
            int row = __builtin_nontemporal_load(&out_idx[p]);
            int iv  = __builtin_nontemporal_load(&in_idx[p]);
            int slot = row * K_FILT + (int)k;
            int c = atomicAdd(&slotCnt[slot], 1);
            if (c == 0)      slot1[slot] = iv;
            else if (c == 1) slot2[slot] = iv;
            else if (c == 2) slot3[slot] = iv;
            else {
                int q = atomicAdd(ovfCur, 1);
                ovf[q] = make_int2(slot, iv);
            }
        }
    }
}

// ---------------------------------------------------------------------------
// conv: wave owns 16 out rows; kf=0..26 branch-free. Per kf: 4 nt slot-word
// loads -> 6 predicated feat loads (absent -> row 0, L1-hot) -> vector-select
// + fp32 merge -> 8 chained MFMA. No LDS, no atomics, no barriers, no
// branches: compiler free to unroll + deep-schedule (~30 loads in flight).
// MFMA layouts r3-verified: A row=lane&15, k=(lane>>4)*8; C/D col=lane&15,
// row=(lane>>4)*4+reg. Out written exactly once (covers poison) + bias.
// ---------------------------------------------------------------------------
__global__ __launch_bounds__(256, 3) void conv_slots(
    const __bf16* __restrict__ featb,   // [N_ACTIVE][64] bf16
    const __bf16* __restrict__ wtb,     // [K][o][i] bf16
    const float* __restrict__ bias,     // [64]
    const int* __restrict__ slotCnt,
    const int* __restrict__ slot1, const int* __restrict__ slot2,
    const int* __restrict__ slot3,
    float* __restrict__ out)            // [N_ACTIVE][64] fp32
{
    const int t = threadIdx.x;
    const int w = t >> 6;
    const int lane = t & 63;
    const int lrow = lane & 15;          // A/out row slot within tile
    const int kg   = lane >> 4;          // k-slice group (0..3)
    const int kgo  = kg * 8;
    const int rowBase = blockIdx.x * 64 + w * 16;
    const int slotBase = (rowBase + lrow) * K_FILT;

    f32x4 acc0 = {0.f,0.f,0.f,0.f}, acc1 = acc0, acc2 = acc0, acc3 = acc0;
    const float b0 = bias[lrow], b1 = bias[16 + lrow],
                b2 = bias[32 + lrow], b3 = bias[48 + lrow];
    const bf16x8 zero8 = {};

    #pragma unroll 3
    for (int kf = 0; kf < K_FILT; ++kf) {
        // ---- slot words (one-touch stream: nt) ----
        const int slot = slotBase + kf;
        int c  = __builtin_nontemporal_load(&slotCnt[slot]);
        int s1 = __builtin_nontemporal_load(&slot1[slot]);
        int s2 = __builtin_nontemporal_load(&slot2[slot]);
        int s3 = __builtin_nontemporal_load(&slot3[slot]);
        int a1 = (c > 0) ? s1 : 0;
        int a2 = (c > 1) ? s2 : 0;
        int a3 = (c > 2) ? s3 : 0;

        // ---- predicated feat loads (row 0 L1-hot when absent) ----
        const __bf16* p1 = featb + (size_t)a1 * 64 + kgo;
        const __bf16* p2 = featb + (size_t)a2 * 64 + kgo;
        const __bf16* p3 = featb + (size_t)a3 * 64 + kgo;
        bf16x8 x0 = *reinterpret_cast<const bf16x8*>(p1);
        bf16x8 x1 = *reinterpret_cast<const bf16x8*>(p1 + 32);
        bf16x8 y0 = *reinterpret_cast<const bf16x8*>(p2);
        bf16x8 y1 = *reinterpret_cast<const bf16x8*>(p2 + 32);
        bf16x8 z0 = *reinterpret_cast<const bf16x8*>(p3);
        bf16x8 z1 = *reinterpret_cast<const bf16x8*>(p3 + 32);

        // ---- B fragments (L2-hot, 216 KB total) ----
        const __bf16* wk = wtb + kf * 4096;
        bf16x8 bf00 = *reinterpret_cast<const bf16x8*>(wk + (lrow)      * 64 + kgo);
        bf16x8 bf01 = *reinterpret_cast<const bf16x8*>(wk + (lrow)      * 64 + 32 + kgo);
        bf16x8 bf10 = *reinterpret_cast<const bf16x8*>(wk + (16 + lrow) * 64 + kgo);
        bf16x8 bf11 = *reinterpret_cast<const bf16x8*>(wk + (16 + lrow) * 64 + 32 + kgo);
        bf16x8 bf20 = *reinterpret_cast<const bf16x8*>(wk + (32 + lrow) * 64 + kgo);
        bf16x8 bf21 = *reinterpret_cast<const bf16x8*>(wk + (32 + lrow) * 64 + 32 + kgo);
        bf16x8 bf30 = *reinterpret_cast<const bf16x8*>(wk + (48 + lrow) * 64 + kgo);
        bf16x8 bf31 = *reinterpret_cast<const bf16x8*>(wk + (48 + lrow) * 64 + 32 + kgo);

        // ---- branch-free select + fp32 merge -> bf16 A ----
        x0 = (c > 0) ? x0 : zero8;  x1 = (c > 0) ? x1 : zero8;
        y0 = (c > 1) ? y0 : zero8;  y1 = (c > 1) ? y1 : zero8;
        z0 = (c > 2) ? z0 : zero8;  z1 = (c > 2) ? z1 : zero8;
        bf16x8 A0, A1;
        #pragma unroll
        for (int j = 0; j < 8; ++j) {
            float f0 = (float)x0[j] + (float)y0[j] + (float)z0[j];
            float f1 = (float)x1[j] + (float)y1[j] + (float)z1[j];
            A0[j] = (__bf16)f0;
            A1[j] = (__bf16)f1;
        }

        // ---- chained MFMA: acc += A(kf) * W(kf) ----
        acc0 = __builtin_amdgcn_mfma_f32_16x16x32_bf16(A0, bf00, acc0, 0, 0, 0);
        acc0 = __builtin_amdgcn_mfma_f32_16x16x32_bf16(A1, bf01, acc0, 0, 0, 0);
        acc1 = __builtin_amdgcn_mfma_f32_16x16x32_bf16(A0, bf10, acc1, 0, 0, 0);
        acc1 = __builtin_amdgcn_mfma_f32_16x16x32_bf16(A1, bf11, acc1, 0, 0, 0);
        acc2 = __builtin_amdgcn_mfma_f32_16x16x32_bf16(A0, bf20, acc2, 0, 0, 0);
        acc2 = __builtin_amdgcn_mfma_f32_16x16x32_bf16(A1, bf21, acc2, 0, 0, 0);
        acc3 = __builtin_amdgcn_mfma_f32_16x16x32_bf16(A0, bf30, acc3, 0, 0, 0);
        acc3 = __builtin_amdgcn_mfma_f32_16x16x32_bf16(A1, bf31, acc3, 0, 0, 0);
    }

    // ---- epilogue: C row = kg*4+r, col = n*16+lrow; nt-write once + bias ----
    #pragma unroll
    for (int r = 0; r < 4; ++r) {
        int gr = rowBase + kg * 4 + r;
        float* orow = out + (size_t)gr * 64;
        __builtin_nontemporal_store(acc0[r] + b0, &orow[lrow]);
        __builtin_nontemporal_store(acc1[r] + b1, &orow[16 + lrow]);
        __builtin_nontemporal_store(acc2[r] + b2, &orow[32 + lrow]);
        __builtin_nontemporal_store(acc3[r] + b3, &orow[48 + lrow]);
    }
}

// ---------------------------------------------------------------------------
// cleanup: overflow entries (4th+ duplicate per slot, E ~ 10K random data).
// 64 threads = 64 out cols; dot(feat[in], Wt[kf][o]) + global fp32 atomicAdd.
// ---------------------------------------------------------------------------
__global__ __launch_bounds__(64) void ovf_cleanup(
    const __bf16* __restrict__ featb, const __bf16* __restrict__ wtb,
    const int2* __restrict__ ovf, const int* __restrict__ ovfCur,
    float* __restrict__ out)
{
    const int n = *ovfCur;
    const int lane = threadIdx.x;
    for (int e = blockIdx.x; e < n; e += gridDim.x) {
        int2 v = ovf[e];
        int slot = v.x, in = v.y;
        int row = slot / K_FILT;
        int kf  = slot - row * K_FILT;
        const __bf16* fp = featb + (size_t)in * 64;
        const __bf16* wp = wtb + kf * 4096 + lane * 64;
        float s = 0.f;
        #pragma unroll
        for (int j = 0; j < 8; ++j) {
            bf16x8 fv = *reinterpret_cast<const bf16x8*>(fp + j * 8);
            bf16x8 wv = *reinterpret_cast<const bf16x8*>(wp + j * 8);
            #pragma unroll
            for (int q = 0; q < 8; ++q) s += (float)fv[q] * (float)wv[q];
        }
        atomicAdd(&out[(size_t)row * 64 + lane], s);
    }
}

extern "C" void kernel_launch(void* const* d_in, const int* in_sizes, int n_in,
                              void* d_out, int out_size, void* d_ws, size_t ws_size,
                              hipStream_t stream) {
    const float* feat    = (const float*)d_in[0];
    const float* weight  = (const float*)d_in[1];
    const float* bias    = (const float*)d_in[2];
    const int*   in_idx  = (const int*)d_in[3];
    const int*   out_idx = (const int*)d_in[4];
    float* out = (float*)d_out;

    // ---- workspace layout (~134 MB) ----
    char* wsb = (char*)d_ws;
    __bf16* featb  = (__bf16*)wsb;                                  // 25,600,000
    __bf16* wtb    = (__bf16*)(wsb + 25600000);                     //    221,184
    int*  slotCnt  = (int*) (wsb + 25600000 + 221184);              // 21,600,000
    int*  slot1    = slotCnt + NSLOT;                               // 21,600,000
    int*  slot2    = slot1 + NSLOT;                                 // 21,600,000
    int*  slot3    = slot2 + NSLOT;                                 // 21,600,000
    int*  ovfCur   = slot3 + NSLOT;                                 // 16 B (padded)
    int2* ovf      = (int2*)(ovfCur + 4);                           // 21,600,000

    hipMemsetAsync(slotCnt, 0, (size_t)NSLOT * 4, stream);
    hipMemsetAsync(ovfCur, 0, 16, stream);

    prep_fused<<<dim3(CF_BLOCKS + CW_BLOCKS + CL_BLOCKS), dim3(256), 0, stream>>>(
        feat, featb, weight, wtb, in_idx, out_idx,
        slotCnt, slot1, slot2, slot3, ovf, ovfCur);
    conv_slots<<<dim3(N_ACTIVE / 64), dim3(256), 0, stream>>>(
        featb, wtb, bias, slotCnt, slot1, slot2, slot3, out);
    ovf_cleanup<<<dim3(2048), dim3(64), 0, stream>>>(featb, wtb, ovf, ovfCur, out);
}

// Round 14
// 627.078 us; speedup vs baseline: 6.8088x; 1.0597x over previous
//
#include <hip/hip_runtime.h>
#include <stdint.h>

#define N_ACTIVE 200000
#define N_IN 64
#define N_OUT 64
#define K_FILT 27
#define R_PAIRS 100000
#define TOTP (K_FILT * R_PAIRS)          // 2,700,000
#define NSLOT (N_ACTIVE * K_FILT)        // 5,400,000 slots (row, kf)

#define CF_BLOCKS (N_ACTIVE * N_IN / 8 / 256)    // 6250
#define CW_BLOCKS K_FILT                          // 27
#define CL_BLOCKS ((TOTP + 255) / 256)            // 10547

typedef __bf16 bf16x8 __attribute__((ext_vector_type(8)));
typedef float f32x4 __attribute__((ext_vector_type(4)));

// ---------------------------------------------------------------------------
// fused prep: convert_feat | convert_wt | claim into PACKED slot table
// slotT[slot] = (cnt, in1, in2, in3); 4th+ duplicate -> overflow list
// ---------------------------------------------------------------------------
__global__ __launch_bounds__(256) void prep_fused(
    const float* __restrict__ feat, __bf16* __restrict__ featb,
    const float* __restrict__ wsrc, __bf16* __restrict__ wt,
    const int* __restrict__ in_idx, const int* __restrict__ out_idx,
    int* __restrict__ slotW,            // int view of slotT
    int2* __restrict__ ovf, int* __restrict__ ovfCur)
{
    int bb = blockIdx.x, t = threadIdx.x;
    if (bb < CF_BLOCKS) {
        int i = bb * 256 + t;
        const f32x4* src = reinterpret_cast<const f32x4*>(feat) + 2 * (size_t)i;
        f32x4 v0 = __builtin_nontemporal_load(src);
        f32x4 v1 = __builtin_nontemporal_load(src + 1);
        bf16x8 o;
        o[0] = (__bf16)v0[0]; o[1] = (__bf16)v0[1]; o[2] = (__bf16)v0[2]; o[3] = (__bf16)v0[3];
        o[4] = (__bf16)v1[0]; o[5] = (__bf16)v1[1]; o[6] = (__bf16)v1[2]; o[7] = (__bf16)v1[3];
        reinterpret_cast<bf16x8*>(featb)[i] = o;
    } else if (bb < CF_BLOCKS + CW_BLOCKS) {
        int kf = bb - CF_BLOCKS;
        const float* wk = wsrc + kf * 4096;
        __bf16* wo = wt + kf * 4096;
        int o = t >> 2, i0 = (t & 3) * 16;
        bf16x8 a, b;
        #pragma unroll
        for (int j = 0; j < 8; ++j) a[j] = (__bf16)wk[(i0 + j) * 64 + o];
        #pragma unroll
        for (int j = 0; j < 8; ++j) b[j] = (__bf16)wk[(i0 + 8 + j) * 64 + o];
        *reinterpret_cast<bf16x8*>(wo + o * 64 + i0) = a;
        *reinterpret_cast<bf16x8*>(wo + o * 64 + i0 + 8) = b;
    } else {
        int p = (bb - CF_BLOCKS - CW_BLOCKS) * 256 + t;
        if (p < TOTP) {
            unsigned k = (unsigned)p / (unsigned)R_PAIRS;
            int row = out_idx[p];
            int iv  = in_idx[p];
            int slot = row * K_FILT + (int)k;
            int c = atomicAdd(&slotW[slot * 4], 1);
            if (c < 3) slotW[slot * 4 + 1 + c] = iv;
            else {
                int q = atomicAdd(ovfCur, 1);
                ovf[q] = make_int2(slot, iv);
            }
        }
    }
}

// ---------------------------------------------------------------------------
// conv: wave owns 16 out rows; kf=0..26 branch-free, unroll 9. Per kf:
// ONE cached int4 slot load -> 6 predicated feat loads (absent -> row 0,
// L1-hot) -> select + fp32 merge -> 8 chained MFMA. No LDS/atomics/barriers.
// MFMA layouts r3-verified: A row=lane&15, k=(lane>>4)*8; C/D col=lane&15,
// row=(lane>>4)*4+reg. Out written exactly once (covers poison) + bias.
// ---------------------------------------------------------------------------
__global__ __launch_bounds__(256, 4) void conv_slots(
    const __bf16* __restrict__ featb,   // [N_ACTIVE][64] bf16
    const __bf16* __restrict__ wtb,     // [K][o][i] bf16
    const float* __restrict__ bias,     // [64]
    const int4* __restrict__ slotT,     // [N_ACTIVE][27] packed
    float* __restrict__ out)            // [N_ACTIVE][64] fp32
{
    const int t = threadIdx.x;
    const int w = t >> 6;
    const int lane = t & 63;
    const int lrow = lane & 15;          // A/out row slot within tile
    const int kg   = lane >> 4;          // k-slice group (0..3)
    const int kgo  = kg * 8;
    const int rowBase = blockIdx.x * 64 + w * 16;
    const int slotBase = (rowBase + lrow) * K_FILT;

    f32x4 acc0 = {0.f,0.f,0.f,0.f}, acc1 = acc0, acc2 = acc0, acc3 = acc0;
    const float b0 = bias[lrow], b1 = bias[16 + lrow],
                b2 = bias[32 + lrow], b3 = bias[48 + lrow];
    const bf16x8 zero8 = {};

    #pragma unroll 9
    for (int kf = 0; kf < K_FILT; ++kf) {
        // ---- ONE packed slot load (cached; L1-reused across kf) ----
        int4 sv = slotT[slotBase + kf];
        int c  = sv.x;
        int a1 = (c > 0) ? sv.y : 0;
        int a2 = (c > 1) ? sv.z : 0;
        int a3 = (c > 2) ? sv.w : 0;

        // ---- predicated feat loads (row 0 L1-hot when absent) ----
        const __bf16* p1 = featb + (size_t)a1 * 64 + kgo;
        const __bf16* p2 = featb + (size_t)a2 * 64 + kgo;
        const __bf16* p3 = featb + (size_t)a3 * 64 + kgo;
        bf16x8 x0 = *reinterpret_cast<const bf16x8*>(p1);
        bf16x8 x1 = *reinterpret_cast<const bf16x8*>(p1 + 32);
        bf16x8 y0 = *reinterpret_cast<const bf16x8*>(p2);
        bf16x8 y1 = *reinterpret_cast<const bf16x8*>(p2 + 32);
        bf16x8 z0 = *reinterpret_cast<const bf16x8*>(p3);
        bf16x8 z1 = *reinterpret_cast<const bf16x8*>(p3 + 32);

        // ---- B fragments (L2-hot, 216 KB total) ----
        const __bf16* wk = wtb + kf * 4096;
        bf16x8 bf00 = *reinterpret_cast<const bf16x8*>(wk + (lrow)      * 64 + kgo);
        bf16x8 bf01 = *reinterpret_cast<const bf16x8*>(wk + (lrow)      * 64 + 32 + kgo);
        bf16x8 bf10 = *reinterpret_cast<const bf16x8*>(wk + (16 + lrow) * 64 + kgo);
        bf16x8 bf11 = *reinterpret_cast<const bf16x8*>(wk + (16 + lrow) * 64 + 32 + kgo);
        bf16x8 bf20 = *reinterpret_cast<const bf16x8*>(wk + (32 + lrow) * 64 + kgo);
        bf16x8 bf21 = *reinterpret_cast<const bf16x8*>(wk + (32 + lrow) * 64 + 32 + kgo);
        bf16x8 bf30 = *reinterpret_cast<const bf16x8*>(wk + (48 + lrow) * 64 + kgo);
        bf16x8 bf31 = *reinterpret_cast<const bf16x8*>(wk + (48 + lrow) * 64 + 32 + kgo);

        // ---- branch-free select + fp32 merge -> bf16 A ----
        x0 = (c > 0) ? x0 : zero8;  x1 = (c > 0) ? x1 : zero8;
        y0 = (c > 1) ? y0 : zero8;  y1 = (c > 1) ? y1 : zero8;
        z0 = (c > 2) ? z0 : zero8;  z1 = (c > 2) ? z1 : zero8;
        bf16x8 A0, A1;
        #pragma unroll
        for (int j = 0; j < 8; ++j) {
            float f0 = (float)x0[j] + (float)y0[j] + (float)z0[j];
            float f1 = (float)x1[j] + (float)y1[j] + (float)z1[j];
            A0[j] = (__bf16)f0;
            A1[j] = (__bf16)f1;
        }

        // ---- chained MFMA: acc += A(kf) * W(kf) ----
        acc0 = __builtin_amdgcn_mfma_f32_16x16x32_bf16(A0, bf00, acc0, 0, 0, 0);
        acc0 = __builtin_amdgcn_mfma_f32_16x16x32_bf16(A1, bf01, acc0, 0, 0, 0);
        acc1 = __builtin_amdgcn_mfma_f32_16x16x32_bf16(A0, bf10, acc1, 0, 0, 0);
        acc1 = __builtin_amdgcn_mfma_f32_16x16x32_bf16(A1, bf11, acc1, 0, 0, 0);
        acc2 = __builtin_amdgcn_mfma_f32_16x16x32_bf16(A0, bf20, acc2, 0, 0, 0);
        acc2 = __builtin_amdgcn_mfma_f32_16x16x32_bf16(A1, bf21, acc2, 0, 0, 0);
        acc3 = __builtin_amdgcn_mfma_f32_16x16x32_bf16(A0, bf30, acc3, 0, 0, 0);
        acc3 = __builtin_amdgcn_mfma_f32_16x16x32_bf16(A1, bf31, acc3, 0, 0, 0);
    }

    // ---- epilogue: C row = kg*4+r, col = n*16+lrow; nt-write once + bias ----
    #pragma unroll
    for (int r = 0; r < 4; ++r) {
        int gr = rowBase + kg * 4 + r;
        float* orow = out + (size_t)gr * 64;
        __builtin_nontemporal_store(acc0[r] + b0, &orow[lrow]);
        __builtin_nontemporal_store(acc1[r] + b1, &orow[16 + lrow]);
        __builtin_nontemporal_store(acc2[r] + b2, &orow[32 + lrow]);
        __builtin_nontemporal_store(acc3[r] + b3, &orow[48 + lrow]);
    }
}

// ---------------------------------------------------------------------------
// cleanup: overflow entries (4th+ duplicate per slot, E ~ 10K random data).
// 64 threads = 64 out cols; dot(feat[in], Wt[kf][o]) + global fp32 atomicAdd.
// ---------------------------------------------------------------------------
__global__ __launch_bounds__(64) void ovf_cleanup(
    const __bf16* __restrict__ featb, const __bf16* __restrict__ wtb,
    const int2* __restrict__ ovf, const int* __restrict__ ovfCur,
    float* __restrict__ out)
{
    const int n = *ovfCur;
    const int lane = threadIdx.x;
    for (int e = blockIdx.x; e < n; e += gridDim.x) {
        int2 v = ovf[e];
        int slot = v.x, in = v.y;
        int row = slot / K_FILT;
        int kf  = slot - row * K_FILT;
        const __bf16* fp = featb + (size_t)in * 64;
        const __bf16* wp = wtb + kf * 4096 + lane * 64;
        float s = 0.f;
        #pragma unroll
        for (int j = 0; j < 8; ++j) {
            bf16x8 fv = *reinterpret_cast<const bf16x8*>(fp + j * 8);
            bf16x8 wv = *reinterpret_cast<const bf16x8*>(wp + j * 8);
            #pragma unroll
            for (int q = 0; q < 8; ++q) s += (float)fv[q] * (float)wv[q];
        }
        atomicAdd(&out[(size_t)row * 64 + lane], s);
    }
}

extern "C" void kernel_launch(void* const* d_in, const int* in_sizes, int n_in,
                              void* d_out, int out_size, void* d_ws, size_t ws_size,
                              hipStream_t stream) {
    const float* feat    = (const float*)d_in[0];
    const float* weight  = (const float*)d_in[1];
    const float* bias    = (const float*)d_in[2];
    const int*   in_idx  = (const int*)d_in[3];
    const int*   out_idx = (const int*)d_in[4];
    float* out = (float*)d_out;

    // ---- workspace layout (~134 MB) ----
    char* wsb = (char*)d_ws;
    __bf16* featb  = (__bf16*)wsb;                                  // 25,600,000
    __bf16* wtb    = (__bf16*)(wsb + 25600000);                     //    221,184
    int*  slotW    = (int*) (wsb + 25600000 + 221184);              // 86,400,000 (int4 packed)
    int*  ovfCur   = slotW + (size_t)NSLOT * 4;                     // 16 B (padded)
    int2* ovf      = (int2*)(ovfCur + 4);                           // 21,600,000

    hipMemsetAsync(slotW, 0, (size_t)NSLOT * 16, stream);
    hipMemsetAsync(ovfCur, 0, 16, stream);

    prep_fused<<<dim3(CF_BLOCKS + CW_BLOCKS + CL_BLOCKS), dim3(256), 0, stream>>>(
        feat, featb, weight, wtb, in_idx, out_idx, slotW, ovf, ovfCur);
    conv_slots<<<dim3(N_ACTIVE / 64), dim3(256), 0, stream>>>(
        featb, wtb, bias, (const int4*)slotW, out);
    ovf_cleanup<<<dim3(2048), dim3(64), 0, stream>>>(featb, wtb, ovf, ovfCur, out);
}